// Round 5
// baseline (112.409 us; speedup 1.0000x reference)
//
#include <hip/hip_runtime.h>

#define BB 8
#define HH 64
#define WW 2048
#define NC 20

// tile: 4 rows x 64 cols per 256-thread block
// depth halo = 4 (9x9 reach, 0.0-padded = exact reference unfold zero-pad:
//   |0 - Dq| = Dq, identical to the reference's padded-neighbor jump)
// label halo = 2 (5x5 reach, 0-padded)
//
// R5 design notes (evidence-driven):
//  - R1: VGPR=48 (8 waves/SIMD), VALUBusy 111%, 65us  -- 4 ops/term
//  - R4: VGPR=108 (4 waves/SIMD), VALUBusy 70%, 68us  -- 2 ops/term
//    => R4 is occupancy/latency-bound, not op-bound.
//  - R3 lesson: cross-iteration reg windows spill to scratch (400MB HBM).
//  => R5 = R4 math + __launch_bounds__(256,6): cap VGPR at 85 (6 waves/SIMD).
//     Allocator sheds pressure by re-reading LDS (rematerializable), which has
//     ample throughput headroom vs the VALU-bound floor.

// dist accumulation for one pixel; W[j] must be indexable with compile-time j.
#define DIST_LOOP(WEXPR)                                                      \
    _Pragma("unroll")                                                         \
    for (int j = 0; j < 25; ++j) {                                            \
        const int jy = j / 5, jx = j % 5;                                     \
        const float Dq = nb[(2 + jy) * 9 + (2 + jx)];                         \
        const float wj = (WEXPR);                                             \
        _Pragma("unroll")                                                     \
        for (int k = 0; k < 25; ++k) {                                        \
            if (k == 12) continue;                                            \
            const int ky = k / 5, kx = k % 5;                                 \
            dist[k] = fmaf(wj, fabsf(nb[(jy + ky) * 9 + (jx + kx)] - Dq),     \
                           dist[k]);                                          \
        }                                                                     \
    }

__global__ __launch_bounds__(256, 6) void knn_refine(
    const float* __restrict__ depth,
    const int*   __restrict__ label,
    const float* __restrict__ wker,
    int*         __restrict__ out)
{
    __shared__ float sD[12][72];
    __shared__ int   sL[8][68];

    const int b  = blockIdx.z;
    const int y0 = blockIdx.y * 4;
    const int x0 = blockIdx.x * 64;
    const int t  = threadIdx.x;

    const float* Db = depth + (size_t)b * (HH * WW);
    const int*   Lb = label + (size_t)b * (HH * WW);

    // ---- stage depth tile (+4 halo), OOB pad = 0.0 ----
    for (int idx = t; idx < 12 * 72; idx += 256) {
        int ry = idx / 72, rx = idx - ry * 72;
        int gyy = y0 + ry - 4, gxx = x0 + rx - 4;
        float v = 0.0f;
        if (gyy >= 0 && gyy < HH && gxx >= 0 && gxx < WW) v = Db[gyy * WW + gxx];
        sD[ry][rx] = v;
    }
    // ---- stage label tile (+2 halo), OOB pad = 0 ----
    for (int idx = t; idx < 8 * 68; idx += 256) {
        int ry = idx / 68, rx = idx - ry * 68;
        int gyy = y0 + ry - 2, gxx = x0 + rx - 2;
        int v = 0;
        if (gyy >= 0 && gyy < HH && gxx >= 0 && gxx < WW) v = Lb[gyy * WW + gxx];
        sL[ry][rx] = v;
    }
    __syncthreads();

    const int px = t & 63;
    const int py = t >> 6;
    const int gy = y0 + py;
    const int gx = x0 + px;

    // kernel weights: uniform address -> scalar loads (SGPR-resident)
    float wv[25];
#pragma unroll
    for (int j = 0; j < 25; ++j) wv[j] = wker[j];

    // 9x9 depth neighborhood; under the VGPR cap the compiler keeps the
    // hot subset in registers and re-reads the rest from LDS in-loop.
    float nb[81];
#pragma unroll
    for (int dy = 0; dy < 9; ++dy)
#pragma unroll
        for (int dx = 0; dx < 9; ++dx)
            nb[dy * 9 + dx] = sD[py + dy][px + dx];

    float dist[25];
#pragma unroll
    for (int k = 0; k < 25; ++k) dist[k] = 0.0f;
    // dist[12] (k-offset (0,0)) stays exactly +0.0: every term is w*|D-D| = 0.

    // block-uniform edge test: only border blocks need conv zero-pad masking.
    const bool edgeBlock = (y0 == 0) | (y0 == HH - 4) | (x0 == 0) | (x0 == WW - 64);

    if (!edgeBlock) {
        // hot path (~82% of blocks): weights straight from SGPRs
        DIST_LOOP(wv[j])
    } else {
        // masked path: anchor-OOB taps contribute 0 (conv zero-pad in p-space)
        float my[5], mx[5];
#pragma unroll
        for (int d = 0; d < 5; ++d) {
            my[d] = ((unsigned)(gy + d - 2) < (unsigned)HH) ? 1.0f : 0.0f;
            mx[d] = ((unsigned)(gx + d - 2) < (unsigned)WW) ? 1.0f : 0.0f;
        }
        float wje[25];
#pragma unroll
        for (int j = 0; j < 25; ++j)
            wje[j] = my[j / 5] * mx[j % 5] * wv[j];   // exact: *1.0 or *0.0
        DIST_LOOP(wje[j])
    }

    // ---- stable top-5 smallest (strict <, ties -> lower k, = lax.top_k) ----
    int labs[5];
#pragma unroll
    for (int r = 0; r < 5; ++r) {
        float best = 3.4e38f;
        int bi = 0;
#pragma unroll
        for (int k = 0; k < 25; ++k) {
            if (dist[k] < best) { best = dist[k]; bi = k; }
        }
        int ky = (bi * 205) >> 10;            // bi / 5 for bi in [0,25)
        int kx = bi - ky * 5;
        labs[r] = (best > 1.0f) ? NC : sL[py + ky][px + kx];
        if (r < 4) {
#pragma unroll
            for (int k = 0; k < 25; ++k)
                if (k == bi) dist[k] = 3.4e38f;
        }
    }

    // ---- majority vote over 5 labels; argmax ties -> lowest class index ----
    int bestLab = 0, bestCnt = 0;
#pragma unroll
    for (int i = 0; i < 5; ++i) {
        const int li = labs[i];
        int c = 0;
#pragma unroll
        for (int j = 0; j < 5; ++j) c += (labs[j] == li) ? 1 : 0;
        if (li < NC && (c > bestCnt || (c == bestCnt && li < bestLab))) {
            bestCnt = c;
            bestLab = li;
        }
    }

    out[(size_t)b * (HH * WW) + (size_t)gy * WW + gx] = bestLab;
}

extern "C" void kernel_launch(void* const* d_in, const int* in_sizes, int n_in,
                              void* d_out, int out_size, void* d_ws, size_t ws_size,
                              hipStream_t stream) {
    const float* depth = (const float*)d_in[0];
    const int*   label = (const int*)d_in[1];
    const float* wker  = (const float*)d_in[2];
    int*         out   = (int*)d_out;

    dim3 grid(WW / 64, HH / 4, BB);
    knn_refine<<<grid, dim3(256), 0, stream>>>(depth, label, wker, out);
}

// Round 6
// 60.985 us; speedup vs baseline: 1.8432x; 1.8432x over previous
//
#include <hip/hip_runtime.h>

#define BB 8
#define HH 64
#define WW 2048
#define NC 20

// tile: 4 rows x 64 cols per 256-thread block
// depth halo = 4 (9x9 reach, 0.0-padded = exact reference unfold zero-pad:
//   |0 - Dq| = Dq, identical to the reference's padded-neighbor jump)
// label halo = 2 (5x5 reach, 0-padded)
//
// R6 design notes (evidence ledger):
//  - R1: 4op/term, VGPR=48, 8 w/SIMD, 65us       (compiler-chosen LDS re-read)
//  - R4: 2op/term, nb[81] reg-resident, VGPR=108, 4 w/SIMD, 68us (latency-bound)
//  - R5: + launch_bounds cap -> 290MB scratch, 112us (caps cause spills, not remat)
//  => R6: runtime (non-unrolled) jy loop; per-iter 5x9 window re-read from LDS.
//     Cross-iteration CSE is structurally impossible -> natural VGPR ~90,
//     LDS reads 625 -> ~230/px, math identical order => absmax 0 preserved.

__global__ void knn_refine(
    const float* __restrict__ depth,
    const int*   __restrict__ label,
    const float* __restrict__ wker,
    int*         __restrict__ out)
{
    __shared__ float sD[12][72];
    __shared__ int   sL[8][68];
    __shared__ float sW[25];

    const int b  = blockIdx.z;
    const int y0 = blockIdx.y * 4;
    const int x0 = blockIdx.x * 64;
    const int t  = threadIdx.x;

    const float* Db = depth + (size_t)b * (HH * WW);
    const int*   Lb = label + (size_t)b * (HH * WW);

    // ---- stage depth tile (+4 halo), OOB pad = 0.0 ----
    for (int idx = t; idx < 12 * 72; idx += 256) {
        int ry = idx / 72, rx = idx - ry * 72;
        int gyy = y0 + ry - 4, gxx = x0 + rx - 4;
        float v = 0.0f;
        if (gyy >= 0 && gyy < HH && gxx >= 0 && gxx < WW) v = Db[gyy * WW + gxx];
        sD[ry][rx] = v;
    }
    // ---- stage label tile (+2 halo), OOB pad = 0 ----
    for (int idx = t; idx < 8 * 68; idx += 256) {
        int ry = idx / 68, rx = idx - ry * 68;
        int gyy = y0 + ry - 2, gxx = x0 + rx - 2;
        int v = 0;
        if (gyy >= 0 && gyy < HH && gxx >= 0 && gxx < WW) v = Lb[gyy * WW + gxx];
        sL[ry][rx] = v;
    }
    // ---- stage weights (uniform-address broadcast reads later) ----
    if (t < 25) sW[t] = wker[t];
    __syncthreads();

    const int px = t & 63;
    const int py = t >> 6;
    const int gy = y0 + py;
    const int gx = x0 + px;

    // x-direction anchor masks (exact 0/1 floats), y computed per-jy inline
    float mx[5];
#pragma unroll
    for (int d = 0; d < 5; ++d)
        mx[d] = ((unsigned)(gx + d - 2) < (unsigned)WW) ? 1.0f : 0.0f;

    float dist[25];
#pragma unroll
    for (int k = 0; k < 25; ++k) dist[k] = 0.0f;
    // dist[12] (k-offset (0,0)) stays exactly +0.0: every term is w*|D-D| = 0.

    // ---- main loop: jy RUNTIME (no unroll) -> no cross-iteration CSE ----
#pragma clang loop unroll(disable)
    for (int jy = 0; jy < 5; ++jy) {
        const float* rp = &sD[py + jy][px];   // runtime base, static offsets below
        float row[5][9];                       // statically indexed only
#pragma unroll
        for (int r = 0; r < 5; ++r)
#pragma unroll
            for (int c = 0; c < 9; ++c)
                row[r][c] = rp[r * 72 + c];

        const float myy = ((unsigned)(gy + jy - 2) < (unsigned)HH) ? 1.0f : 0.0f;

#pragma unroll
        for (int jx = 0; jx < 5; ++jx) {
            const float wj = myy * mx[jx] * sW[jy * 5 + jx];  // exact *1.0/0.0
            const float Dq = row[2][jx + 2];
#pragma unroll
            for (int k = 0; k < 25; ++k) {
                if (k == 12) continue;
                const int ky = k / 5, kx = k % 5;
                dist[k] = fmaf(wj, fabsf(row[ky][jx + kx] - Dq), dist[k]);
            }
        }
    }

    // ---- stable top-5 smallest (strict <, ties -> lower k, = lax.top_k) ----
    int labs[5];
#pragma unroll
    for (int r = 0; r < 5; ++r) {
        float best = 3.4e38f;
        int bi = 0;
#pragma unroll
        for (int k = 0; k < 25; ++k) {
            if (dist[k] < best) { best = dist[k]; bi = k; }
        }
        int ky = (bi * 205) >> 10;            // bi / 5 for bi in [0,25)
        int kx = bi - ky * 5;
        labs[r] = (best > 1.0f) ? NC : sL[py + ky][px + kx];
        if (r < 4) {
#pragma unroll
            for (int k = 0; k < 25; ++k)
                if (k == bi) dist[k] = 3.4e38f;
        }
    }

    // ---- majority vote over 5 labels; argmax ties -> lowest class index ----
    int bestLab = 0, bestCnt = 0;
#pragma unroll
    for (int i = 0; i < 5; ++i) {
        const int li = labs[i];
        int c = 0;
#pragma unroll
        for (int j = 0; j < 5; ++j) c += (labs[j] == li) ? 1 : 0;
        if (li < NC && (c > bestCnt || (c == bestCnt && li < bestLab))) {
            bestCnt = c;
            bestLab = li;
        }
    }

    out[(size_t)b * (HH * WW) + (size_t)gy * WW + gx] = bestLab;
}

extern "C" void kernel_launch(void* const* d_in, const int* in_sizes, int n_in,
                              void* d_out, int out_size, void* d_ws, size_t ws_size,
                              hipStream_t stream) {
    const float* depth = (const float*)d_in[0];
    const int*   label = (const int*)d_in[1];
    const float* wker  = (const float*)d_in[2];
    int*         out   = (int*)d_out;

    dim3 grid(WW / 64, HH / 4, BB);
    knn_refine<<<grid, dim3(256), 0, stream>>>(depth, label, wker, out);
}